// Round 10
// baseline (513.734 us; speedup 1.0000x reference)
//
#include <hip/hip_runtime.h>
#include <hip/hip_bf16.h>
#include <math.h>

typedef __bf16 bf16;
typedef bf16 bf16x8 __attribute__((ext_vector_type(8)));
typedef float floatx4 __attribute__((ext_vector_type(4)));

#define NN 50000
#define EE 800000
#define DIMC 256
#define FFC 1024

typedef __attribute__((address_space(3))) unsigned int lds_u32;
typedef __attribute__((address_space(1))) unsigned int gbl_u32;

static __device__ __forceinline__ void glds16(const bf16* g, bf16* l) {
    __builtin_amdgcn_global_load_lds((const gbl_u32*)g, (lds_u32*)l, 16, 0, 0);
}

static __device__ __forceinline__ unsigned short f2b(float f) {
    bf16 b = (bf16)f;
    return __builtin_bit_cast(unsigned short, b);
}
static __device__ __forceinline__ float b2f_lo(unsigned u) { return __uint_as_float(u << 16); }
static __device__ __forceinline__ float b2f_hi(unsigned u) { return __uint_as_float(u & 0xffff0000u); }

static __device__ __forceinline__ float gelu_f(float v) {
    float z = -1.5957691216f * v - 0.0713548163f * v * v * v;
    return v / (1.f + __expf(z));
}

// ---------------- cast fp32 -> bf16 (4 elems/thread) + fused edge-degree count ----------------
__global__ __launch_bounds__(256)
void k_cast_count(const float* __restrict__ in, bf16* __restrict__ out, long n4,
                  const int* __restrict__ dst, unsigned* __restrict__ deg) {
    long i = (long)blockIdx.x * 256 + threadIdx.x;
    if (i < EE) atomicAdd(&deg[dst[(int)i]], 1u);
    if (i >= n4) return;
    float4 v = ((const float4*)in)[i];
    uint2 p;
    p.x = (unsigned)f2b(v.x) | ((unsigned)f2b(v.y) << 16);
    p.y = (unsigned)f2b(v.z) | ((unsigned)f2b(v.w) << 16);
    ((uint2*)out)[i] = p;
}

// ---------------- all three transpose+casts in one launch ----------------
__global__ __launch_bounds__(256)
void k_tcast_all(const float* __restrict__ W, bf16* __restrict__ WT,
                 const float* __restrict__ W1, bf16* __restrict__ W1T,
                 const float* __restrict__ W2, bf16* __restrict__ W2T) {
    __shared__ float t[32][33];
    int b = blockIdx.x;
    const float* in; bf16* out; int K, Nc, bx, by;
    if (b < 64)        { in = W;  out = WT;  K = 256;  Nc = 256;  bx = b & 7;  by = b >> 3; }
    else if (b < 320)  { b -= 64;  in = W1; out = W1T; K = 256;  Nc = 1024; bx = b & 31; by = b >> 5; }
    else               { b -= 320; in = W2; out = W2T; K = 1024; Nc = 256;  bx = b & 7;  by = b >> 3; }
    int n0 = bx * 32, k0 = by * 32;
    int tx = threadIdx.x & 31, ty = threadIdx.x >> 5;
#pragma unroll
    for (int i = 0; i < 4; ++i)
        t[ty + i * 8][tx] = in[(long)(k0 + ty + i * 8) * Nc + n0 + tx];
    __syncthreads();
#pragma unroll
    for (int i = 0; i < 4; ++i)
        out[(long)(n0 + ty + i * 8) * K + k0 + tx] = (bf16)t[tx][ty + i * 8];
}

// ---------------- bf16 MFMA GEMM: C[M][Nc] = A[M][K] * BT[Nc][K]^T ----------------
template <int EPI>
__global__ __launch_bounds__(256)
void k_gemmA(const bf16* __restrict__ A, const bf16* __restrict__ BT,
             bf16* __restrict__ C, const float* __restrict__ bias,
             const float* __restrict__ avs, const float* __restrict__ avd,
             float* __restrict__ asrcO, float* __restrict__ adstO,
             int M, int K, int Nc) {
    __shared__ __attribute__((aligned(16))) bf16 smem[17408];  // 34816 B
    bf16* As = smem;          // [128][64]
    bf16* Bs = smem + 8192;   // [128][64]
    const int tid = threadIdx.x;
    const int w = tid >> 6, lane = tid & 63;
    const int gm = blockIdx.x * 128, gn = blockIdx.y * 128;
    const int wm = (w >> 1) * 64, wn = (w & 1) * 64;
    const int lr = lane & 15, lkc = lane >> 4;

    long aoff[4], boff[4];
#pragma unroll
    for (int j = 0; j < 4; ++j) {
        int s = w * 4 + j;
        int r = s * 8 + (lane >> 3);
        int kc = ((lane & 7) ^ (r & 7)) * 8;
        aoff[j] = (long)min(gm + r, M - 1) * K + kc;
        boff[j] = (long)(gn + r) * K + kc;
    }

    floatx4 acc[4][4];
#pragma unroll
    for (int a = 0; a < 4; ++a)
#pragma unroll
        for (int b = 0; b < 4; ++b) acc[a][b] = floatx4{0.f, 0.f, 0.f, 0.f};

    for (int k0 = 0; k0 < K; k0 += 64) {
        if (k0) __syncthreads();
#pragma unroll
        for (int j = 0; j < 4; ++j) {
            int s = w * 4 + j;
            glds16(A + aoff[j] + k0, As + s * 512);
            glds16(BT + boff[j] + k0, Bs + s * 512);
        }
        __syncthreads();
#pragma unroll
        for (int kk = 0; kk < 2; ++kk) {
            bf16x8 af[4], bv[4];
#pragma unroll
            for (int mi = 0; mi < 4; ++mi) {
                int r = wm + mi * 16 + lr;
                int ch = (kk * 4 + lkc) ^ (r & 7);
                af[mi] = *(const bf16x8*)(As + r * 64 + ch * 8);
            }
#pragma unroll
            for (int ni = 0; ni < 4; ++ni) {
                int r = wn + ni * 16 + lr;
                int ch = (kk * 4 + lkc) ^ (r & 7);
                bv[ni] = *(const bf16x8*)(Bs + r * 64 + ch * 8);
            }
#pragma unroll
            for (int mi = 0; mi < 4; ++mi)
#pragma unroll
                for (int ni = 0; ni < 4; ++ni)
                    acc[mi][ni] = __builtin_amdgcn_mfma_f32_16x16x32_bf16(af[mi], bv[ni], acc[mi][ni], 0, 0, 0);
        }
    }

    __syncthreads();
    bf16* cs = smem;  // [128][136]
#pragma unroll
    for (int ni = 0; ni < 4; ++ni) {
        const int cl = wn + ni * 16 + lr;
        const float bvs = (EPI == 1) ? bias[gn + cl] : 0.f;
#pragma unroll
        for (int mi = 0; mi < 4; ++mi)
#pragma unroll
            for (int i = 0; i < 4; ++i) {
                int rl = wm + mi * 16 + lkc * 4 + i;
                float v = acc[mi][ni][i] + bvs;
                if (EPI == 1) v = gelu_f(v);
                cs[rl * 136 + cl] = (bf16)v;
            }
    }
    __syncthreads();

    const int c8 = (lane & 15) * 8;
    float as8[8], ad8[8];
    int hd = 0;
    if (EPI == 0) {
        hd = (gn >> 6) + ((lane & 15) >> 3);
        const int cb = hd * 64 + (c8 & 63);
#pragma unroll
        for (int i = 0; i < 8; ++i) { as8[i] = avs[cb + i]; ad8[i] = avd[cb + i]; }
    }

#pragma unroll
    for (int t = 0; t < 8; ++t) {
        int rl = w * 32 + t * 4 + (lane >> 4);
        int grow = gm + rl;
        uint4 val = *(const uint4*)(cs + rl * 136 + c8);
        if (grow < M) *(uint4*)(C + (long)grow * Nc + gn + c8) = val;
        if (EPI == 0) {
            float h0 = b2f_lo(val.x), h1 = b2f_hi(val.x), h2 = b2f_lo(val.y), h3 = b2f_hi(val.y);
            float h4 = b2f_lo(val.z), h5 = b2f_hi(val.z), h6 = b2f_lo(val.w), h7 = b2f_hi(val.w);
            float ds = h0 * as8[0] + h1 * as8[1] + h2 * as8[2] + h3 * as8[3]
                     + h4 * as8[4] + h5 * as8[5] + h6 * as8[6] + h7 * as8[7];
            float dd = h0 * ad8[0] + h1 * ad8[1] + h2 * ad8[2] + h3 * ad8[3]
                     + h4 * ad8[4] + h5 * ad8[5] + h6 * ad8[6] + h7 * ad8[7];
#pragma unroll
            for (int off = 1; off < 8; off <<= 1) { ds += __shfl_xor(ds, off); dd += __shfl_xor(dd, off); }
            if ((lane & 7) == 0 && grow < M) {
                asrcO[grow * 4 + hd] = ds;
                adstO[grow * 4 + hd] = dd;
            }
        }
    }
}

// ---------------- fused FFN v8: CHUNK=64 (16 chunks, half the barriers of v7) ----------------
// 64 rows/block, 512 thr (8 waves = 4mg x 2nh). Per chunk: stage 64KB of W
// (8 glds16/thread), drain, 32 MFMA/wave (16 stageA + 16 stageB) across 2
// phases. Same total work as v7, amortized over 48 barriers instead of 64.
// acts = TWO copies of the R5-proven [64][32] f32 swizzled layout (halves of
// the 64-wide chunk); wave nh writes half nh, all waves read both halves.
// W1 [64][256] swizzle g^=(r&7); W2 [256][64] swizzle g^=((r>>1)&7) — same
// involutions staged via pre-swizzled global source. LDS 81920 B -> 2 bl/CU.
#define STAGE_W64(cc) do {                                                      \
    _Pragma("unroll")                                                           \
    for (int j = 0; j < 4; ++j) {                                               \
        int sg = w * 4 + j;                                                     \
        int r = sg * 2 + (lane >> 5);                                           \
        int g = (lane & 31) ^ (r & 7);                                          \
        glds16(W1T + (long)((cc) * 64 + r) * DIMC + g * 8, w1s + sg * 512);     \
    }                                                                           \
    _Pragma("unroll")                                                           \
    for (int j = 0; j < 4; ++j) {                                               \
        int sg = w * 4 + j;                                                     \
        int r = sg * 8 + (lane >> 3);                                           \
        int g = (lane & 7) ^ ((r >> 1) & 7);                                    \
        glds16(W2T + (long)r * FFC + (cc) * 64 + g * 8, w2s + sg * 512);        \
    }                                                                           \
} while (0)

__global__ __launch_bounds__(512)
void k_ffn(const bf16* __restrict__ x1b, const bf16* __restrict__ W1T,
           const bf16* __restrict__ W2T, const float* __restrict__ b1,
           const float* __restrict__ b2, const float* __restrict__ x,
           const float* __restrict__ lng, const float* __restrict__ lnb,
           float* __restrict__ out, int M) {
    __shared__ __attribute__((aligned(16))) bf16 smem[40960];  // 81920 B
    float* actf = (float*)smem;      // 2 x [64][32] f32 swizzled halves, 16 KB
    bf16* w1s = smem + 8192;         // [64][256], 32 KB
    bf16* w2s = smem + 24576;        // [256][64], 32 KB
    const int tid = threadIdx.x;
    const int w = tid >> 6, lane = tid & 63;
    const int lr = lane & 15, lkc = lane >> 4;
    const int mg = w >> 1, nh = w & 1;
    const int gm = blockIdx.x * 64;

    // persistent x1 A-fragments: rows [gm+mg*16, +16), K=256
    bf16x8 xf[8];
    {
        long rb = (long)min(gm + mg * 16 + lr, M - 1) * DIMC;
#pragma unroll
        for (int kf = 0; kf < 8; ++kf)
            xf[kf] = *(const bf16x8*)(x1b + rb + kf * 32 + lkc * 8);
    }

    floatx4 accB[8];
#pragma unroll
    for (int i = 0; i < 8; ++i) accB[i] = floatx4{0.f, 0.f, 0.f, 0.f};

    const int rb0 = nh * 32 + lr;        // W1 frag row, chunk-col frag 0
    const int rb1 = nh * 32 + 16 + lr;   // frag 1 (same &7 as rb0)
    const int rAct = mg * 16 + lr;       // acts read row

    for (int c = 0; c < 16; ++c) {
        if (c) __syncthreads();   // all reads of W[c-1] + acts done before overwrite
        STAGE_W64(c);
        __syncthreads();          // W chunk visible (drain)

        // stage A: 16 MFMA, 2 independent chains (one per col-frag)
        floatx4 a0 = floatx4{0.f, 0.f, 0.f, 0.f}, a1 = a0;
#pragma unroll
        for (int kf = 0; kf < 8; ++kf) {
            int g = kf * 4 + lkc;
            bf16x8 bv0 = *(const bf16x8*)(w1s + rb0 * 256 + ((g ^ (rb0 & 7)) * 8));
            bf16x8 bv1 = *(const bf16x8*)(w1s + rb1 * 256 + ((g ^ (rb1 & 7)) * 8));
            a0 = __builtin_amdgcn_mfma_f32_16x16x32_bf16(xf[kf], bv0, a0, 0, 0, 0);
            a1 = __builtin_amdgcn_mfma_f32_16x16x32_bf16(xf[kf], bv1, a1, 0, 0, 0);
        }
        float b1v0 = b1[c * 64 + nh * 32 + lr];
        float b1v1 = b1[c * 64 + nh * 32 + 16 + lr];
        float* ah = actf + nh * 2048;    // this wave's half
#pragma unroll
        for (int i = 0; i < 4; ++i) {
            int r = mg * 16 + lkc * 4 + i;
            int e0 = lr, e1 = 16 + lr;
            ah[r * 32 + (((e0 >> 2) ^ (r & 7)) << 2) + (e0 & 3)] = gelu_f(a0[i] + b1v0);
            ah[r * 32 + (((e1 >> 2) ^ (r & 7)) << 2) + (e1 & 3)] = gelu_f(a1[i] + b1v1);
        }
        __syncthreads();          // acts visible

        // stage B: 4 conflict-free b128 acts reads (both halves) + 16 MFMA
        bf16x8 af0, af1;
        {
            int g0 = (lkc * 2) ^ (rAct & 7);
            int g1 = (lkc * 2 + 1) ^ (rAct & 7);
            const float* h0p = actf;
            const float* h1p = actf + 2048;
            float4 lo = *(const float4*)(h0p + rAct * 32 + g0 * 4);
            float4 hi = *(const float4*)(h0p + rAct * 32 + g1 * 4);
            af0[0] = (bf16)lo.x; af0[1] = (bf16)lo.y; af0[2] = (bf16)lo.z; af0[3] = (bf16)lo.w;
            af0[4] = (bf16)hi.x; af0[5] = (bf16)hi.y; af0[6] = (bf16)hi.z; af0[7] = (bf16)hi.w;
            lo = *(const float4*)(h1p + rAct * 32 + g0 * 4);
            hi = *(const float4*)(h1p + rAct * 32 + g1 * 4);
            af1[0] = (bf16)lo.x; af1[1] = (bf16)lo.y; af1[2] = (bf16)lo.z; af1[3] = (bf16)lo.w;
            af1[4] = (bf16)hi.x; af1[5] = (bf16)hi.y; af1[6] = (bf16)hi.z; af1[7] = (bf16)hi.w;
        }
#pragma unroll
        for (int ni = 0; ni < 8; ++ni) {
            int rb = nh * 128 + ni * 16 + lr;
            int sw = (rb >> 1) & 7;
            bf16x8 bv0 = *(const bf16x8*)(w2s + rb * 64 + ((lkc ^ sw) * 8));
            bf16x8 bv1 = *(const bf16x8*)(w2s + rb * 64 + (((4 + lkc) ^ sw) * 8));
            accB[ni] = __builtin_amdgcn_mfma_f32_16x16x32_bf16(af0, bv0, accB[ni], 0, 0, 0);
            accB[ni] = __builtin_amdgcn_mfma_f32_16x16x32_bf16(af1, bv1, accB[ni], 0, 0, 0);
        }
    }

    // ---- epilogue: acc+b2 -> LDS bf16 [64][264] -> LN2 + residual
    __syncthreads();   // last stage-B reads done before cs overwrite
    bf16* cs = smem;   // [64][264] = 33792 B
#pragma unroll
    for (int ni = 0; ni < 8; ++ni) {
        int col = nh * 128 + ni * 16 + lr;
        float b2v = b2[col];
#pragma unroll
        for (int i = 0; i < 4; ++i) {
            int rl = mg * 16 + lkc * 4 + i;
            cs[rl * 264 + col] = (bf16)(accB[ni][i] + b2v);
        }
    }
    __syncthreads();
    float4 g4 = *(const float4*)(lng + lane * 4);
    float4 lb4 = *(const float4*)(lnb + lane * 4);
#pragma unroll 1
    for (int t = 0; t < 8; ++t) {
        int r = w * 8 + t;
        int grow = gm + r;
        long base = (long)min(grow, M - 1) * DIMC + lane * 4;
        uint2 cu = *(const uint2*)(cs + r * 264 + lane * 4);
        uint2 xu = *(const uint2*)(x1b + base);
        float v0 = b2f_lo(cu.x) + b2f_lo(xu.x);
        float v1 = b2f_hi(cu.x) + b2f_hi(xu.x);
        float v2 = b2f_lo(cu.y) + b2f_lo(xu.y);
        float v3 = b2f_hi(cu.y) + b2f_hi(xu.y);
        float s1 = v0 + v1 + v2 + v3;
        float s2 = v0 * v0 + v1 * v1 + v2 * v2 + v3 * v3;
#pragma unroll
        for (int off = 1; off < 64; off <<= 1) { s1 += __shfl_xor(s1, off); s2 += __shfl_xor(s2, off); }
        float mu = s1 * (1.f / DIMC);
        float rs = rsqrtf(s2 * (1.f / DIMC) - mu * mu + 1e-5f);
        float4 xr = *(const float4*)(x + base);
        float4 o;
        o.x = (v0 - mu) * rs * g4.x + lb4.x + xr.x;
        o.y = (v1 - mu) * rs * g4.y + lb4.y + xr.y;
        o.z = (v2 - mu) * rs * g4.z + lb4.z + xr.z;
        o.w = (v3 - mu) * rs * g4.w + lb4.w + xr.w;
        if (grow < M) *(float4*)(out + (long)grow * DIMC + lane * 4) = o;
    }
}

// ---------------- parallel 3-phase CSR scan ----------------
__global__ __launch_bounds__(1024)
void k_scan1(const unsigned* __restrict__ deg, unsigned* __restrict__ rowoff,
             unsigned* __restrict__ cursor, unsigned* __restrict__ bsum) {
    __shared__ unsigned wsum[16], wscan[16];
    int tid = threadIdx.x, lane = tid & 63, wid = tid >> 6;
    int i = blockIdx.x * 1024 + tid;
    unsigned v = (i < NN) ? deg[i] : 0u;
    unsigned s = v;
    for (int off = 1; off < 64; off <<= 1) {
        unsigned t = __shfl_up(s, off);
        if (lane >= off) s += t;
    }
    if (lane == 63) wsum[wid] = s;
    __syncthreads();
    if (wid == 0) {
        unsigned t = (lane < 16) ? wsum[lane] : 0u;
        unsigned ts = t;
        for (int off = 1; off < 16; off <<= 1) {
            unsigned u2 = __shfl_up(ts, off);
            if (lane >= off) ts += u2;
        }
        if (lane < 16) wscan[lane] = ts;
    }
    __syncthreads();
    unsigned basew = (wid > 0) ? wscan[wid - 1] : 0u;
    unsigned excl = basew + (s - v);
    if (i < NN) { rowoff[i] = excl; cursor[i] = excl; }
    if (tid == 0) bsum[blockIdx.x] = wscan[15];
}

__global__ __launch_bounds__(64)
void k_scan2(unsigned* __restrict__ bsum, unsigned* __restrict__ rowoff) {
    int lane = threadIdx.x;
    unsigned v = (lane < 49) ? bsum[lane] : 0u;
    unsigned s = v;
    for (int off = 1; off < 64; off <<= 1) {
        unsigned t = __shfl_up(s, off);
        if (lane >= off) s += t;
    }
    if (lane < 49) bsum[lane] = s - v;
    if (lane == 48) rowoff[NN] = s;
}

__global__ __launch_bounds__(256)
void k_scan3(const unsigned* __restrict__ bsum, unsigned* __restrict__ rowoff,
             unsigned* __restrict__ cursor) {
    int i = blockIdx.x * 256 + threadIdx.x;
    if (i < NN) {
        unsigned o = bsum[i >> 10];
        rowoff[i] += o;
        cursor[i] += o;
    }
}

// fill CSR + precompute per-edge src-logits in CSR order (coalesced read in agg)
__global__ __launch_bounds__(256)
void k_fill(const int* __restrict__ src, const int* __restrict__ dst,
            const float* __restrict__ asrc, unsigned* __restrict__ cursor,
            unsigned* __restrict__ elist, float4* __restrict__ evals) {
    int e = blockIdx.x * 256 + threadIdx.x;
    if (e < EE) {
        int s = src[e];
        unsigned p = atomicAdd(&cursor[dst[e]], 1u);
        elist[p] = (unsigned)s;
        evals[p] = *(const float4*)(asrc + (long)s * 4);
    }
}

// ---------------- per-node: single-pass softmax-aggregate + residual + LN1 ----------------
__global__ __launch_bounds__(256)
void k_agg_ln1(const unsigned* __restrict__ rowoff, const unsigned* __restrict__ elist,
               const float* __restrict__ evals, const float* __restrict__ adst,
               const bf16* __restrict__ hb, const float* __restrict__ x,
               const float* __restrict__ gatb, const float* __restrict__ lng,
               const float* __restrict__ lnb, bf16* __restrict__ x1b) {
    int node = (blockIdx.x * 256 + threadIdx.x) >> 6;
    int lane = threadIdx.x & 63;
    if (node >= NN) return;
    int beg = (int)rowoff[node], end = (int)rowoff[node + 1];
    int head = lane >> 4;
    float ad = adst[node * 4 + head];
    const int c = lane * 4;
    const bf16* hc = hb + c;
    const int bl = lane & 48;

    float dsum = 0.f;
    float a0 = 0.f, a1 = 0.f, a2 = 0.f, a3 = 0.f;

    for (int c0 = beg; c0 < end; c0 += 16) {
        int take = end - c0; if (take > 16) take = 16;
        int jj = c0 + (lane & 15);
        float ex = 0.f; int s = 0;
        if (jj < end) {
            s = (int)elist[jj];
            float e = evals[(long)jj * 4 + head] + ad;   // coalesced (CSR-ordered)
            e = (e > 0.f) ? e : 0.2f * e;
            ex = __expf(e);
        }
        dsum += ex;
        if (take == 16) {
#pragma unroll
            for (int j = 0; j < 16; ++j) {
                float al = __shfl(ex, bl + j);
                int sj = __shfl(s, bl + j);
                uint2 u = *(const uint2*)(hc + (long)sj * DIMC);
                a0 += al * b2f_lo(u.x);
                a1 += al * b2f_hi(u.x);
                a2 += al * b2f_lo(u.y);
                a3 += al * b2f_hi(u.y);
            }
        } else {
            for (int j = 0; j < take; ++j) {
                float al = __shfl(ex, bl + j);
                int sj = __shfl(s, bl + j);
                uint2 u = *(const uint2*)(hc + (long)sj * DIMC);
                a0 += al * b2f_lo(u.x);
                a1 += al * b2f_hi(u.x);
                a2 += al * b2f_lo(u.y);
                a3 += al * b2f_hi(u.y);
            }
        }
    }
    dsum += __shfl_xor(dsum, 1);
    dsum += __shfl_xor(dsum, 2);
    dsum += __shfl_xor(dsum, 4);
    dsum += __shfl_xor(dsum, 8);
    float invd = 1.f / (dsum + 1e-16f);
    a0 *= invd; a1 *= invd; a2 *= invd; a3 *= invd;

    long base = (long)node * DIMC + c;
    float4 xr = *(const float4*)(x + base);
    float4 gb = *(const float4*)(gatb + c);
    float v0 = xr.x + a0 + gb.x;
    float v1 = xr.y + a1 + gb.y;
    float v2 = xr.z + a2 + gb.z;
    float v3 = xr.w + a3 + gb.w;
    float s1 = v0 + v1 + v2 + v3;
    float s2 = v0 * v0 + v1 * v1 + v2 * v2 + v3 * v3;
    for (int off = 1; off < 64; off <<= 1) { s1 += __shfl_xor(s1, off); s2 += __shfl_xor(s2, off); }
    float mu = s1 * (1.f / DIMC);
    float rs = rsqrtf(s2 * (1.f / DIMC) - mu * mu + 1e-5f);
    float4 g4 = *(const float4*)(lng + c);
    float4 b4 = *(const float4*)(lnb + c);
    float y0 = (v0 - mu) * rs * g4.x + b4.x;
    float y1 = (v1 - mu) * rs * g4.y + b4.y;
    float y2 = (v2 - mu) * rs * g4.z + b4.z;
    float y3 = (v3 - mu) * rs * g4.w + b4.w;
    uint2 p;
    p.x = (unsigned)f2b(y0) | ((unsigned)f2b(y1) << 16);
    p.y = (unsigned)f2b(y2) | ((unsigned)f2b(y3) << 16);
    *(uint2*)(x1b + base) = p;
}

extern "C" void kernel_launch(void* const* d_in, const int* in_sizes, int n_in,
                              void* d_out, int out_size, void* d_ws, size_t ws_size,
                              hipStream_t stream) {
    const float* x    = (const float*)d_in[0];
    const int*   ei   = (const int*)d_in[1];
    const float* W    = (const float*)d_in[2];
    const float* a_s  = (const float*)d_in[3];
    const float* a_d  = (const float*)d_in[4];
    const float* gatb = (const float*)d_in[5];
    const float* lng  = (const float*)d_in[6];
    const float* lnb  = (const float*)d_in[7];
    const float* W1   = (const float*)d_in[8];
    const float* b1   = (const float*)d_in[9];
    const float* W2   = (const float*)d_in[10];
    const float* b2   = (const float*)d_in[11];
    float* out = (float*)d_out;
    char* ws = (char*)d_ws;

    bf16*     xb     = (bf16*)(ws + 0L);
    bf16*     hb     = (bf16*)(ws + 25600000L);
    bf16*     x1b    = (bf16*)(ws + 51200000L);
    unsigned* bsum   = (unsigned*)(ws + 76800000L);   // 49 entries
    float4*   evals  = (float4*)(ws + 77000032L);     // [E] float4 = 12.8 MB (dead region)
    float*    asrc   = (float*)(ws + 179200000L);
    float*    adst   = (float*)(ws + 180000000L);
    unsigned* deg    = (unsigned*)(ws + 180800000L);
    unsigned* cursor = (unsigned*)(ws + 181000192L);
    unsigned* rowoff = (unsigned*)(ws + 181200384L);
    unsigned* elist  = (unsigned*)(ws + 181400832L);
    bf16*     WT     = (bf16*)(ws + 184600832L);
    bf16*     W1T    = (bf16*)(ws + 184731904L);
    bf16*     W2T    = (bf16*)(ws + 185256192L);

    const int* esrc = ei;
    const int* edst = ei + EE;

    hipMemsetAsync(deg, 0, NN * sizeof(unsigned), stream);
    k_cast_count<<<12500, 256, 0, stream>>>(x, xb, (long)NN * DIMC / 4, edst, deg);
    k_tcast_all<<<576, 256, 0, stream>>>(W, WT, W1, W1T, W2, W2T);

    dim3 g1(391, 2);
    k_gemmA<0><<<g1, 256, 0, stream>>>(xb, WT, hb, nullptr, a_s, a_d, asrc, adst, NN, DIMC, DIMC);

    k_scan1<<<49, 1024, 0, stream>>>(deg, rowoff, cursor, bsum);
    k_scan2<<<1, 64, 0, stream>>>(bsum, rowoff);
    k_scan3<<<196, 256, 0, stream>>>(bsum, rowoff, cursor);
    k_fill<<<3125, 256, 0, stream>>>(esrc, edst, asrc, cursor, elist, evals);

    k_agg_ln1<<<12500, 256, 0, stream>>>(rowoff, elist, (const float*)evals, adst, hb, x, gatb, lng, lnb, x1b);

    k_ffn<<<782, 512, 0, stream>>>(x1b, W1T, W2T, b1, b2, x, lng, lnb, out, NN);
}

// Round 11
// 433.501 us; speedup vs baseline: 1.1851x; 1.1851x over previous
//
#include <hip/hip_runtime.h>
#include <hip/hip_bf16.h>
#include <math.h>

typedef __bf16 bf16;
typedef bf16 bf16x8 __attribute__((ext_vector_type(8)));
typedef float floatx4 __attribute__((ext_vector_type(4)));

#define NN 50000
#define EE 800000
#define DIMC 256
#define FFC 1024

typedef __attribute__((address_space(3))) unsigned int lds_u32;
typedef __attribute__((address_space(1))) unsigned int gbl_u32;

static __device__ __forceinline__ void glds16(const bf16* g, bf16* l) {
    __builtin_amdgcn_global_load_lds((const gbl_u32*)g, (lds_u32*)l, 16, 0, 0);
}

static __device__ __forceinline__ unsigned short f2b(float f) {
    bf16 b = (bf16)f;
    return __builtin_bit_cast(unsigned short, b);
}
static __device__ __forceinline__ float b2f_lo(unsigned u) { return __uint_as_float(u << 16); }
static __device__ __forceinline__ float b2f_hi(unsigned u) { return __uint_as_float(u & 0xffff0000u); }

static __device__ __forceinline__ float gelu_f(float v) {
    float z = -1.5957691216f * v - 0.0713548163f * v * v * v;
    return v / (1.f + __expf(z));
}

// ---------------- cast fp32 -> bf16 (4 elems/thread) + fused edge-degree count ----------------
__global__ __launch_bounds__(256)
void k_cast_count(const float* __restrict__ in, bf16* __restrict__ out, long n4,
                  const int* __restrict__ dst, unsigned* __restrict__ deg) {
    long i = (long)blockIdx.x * 256 + threadIdx.x;
    if (i < EE) atomicAdd(&deg[dst[(int)i]], 1u);
    if (i >= n4) return;
    float4 v = ((const float4*)in)[i];
    uint2 p;
    p.x = (unsigned)f2b(v.x) | ((unsigned)f2b(v.y) << 16);
    p.y = (unsigned)f2b(v.z) | ((unsigned)f2b(v.w) << 16);
    ((uint2*)out)[i] = p;
}

// ---------------- all three transpose+casts in one launch ----------------
__global__ __launch_bounds__(256)
void k_tcast_all(const float* __restrict__ W, bf16* __restrict__ WT,
                 const float* __restrict__ W1, bf16* __restrict__ W1T,
                 const float* __restrict__ W2, bf16* __restrict__ W2T) {
    __shared__ float t[32][33];
    int b = blockIdx.x;
    const float* in; bf16* out; int K, Nc, bx, by;
    if (b < 64)        { in = W;  out = WT;  K = 256;  Nc = 256;  bx = b & 7;  by = b >> 3; }
    else if (b < 320)  { b -= 64;  in = W1; out = W1T; K = 256;  Nc = 1024; bx = b & 31; by = b >> 5; }
    else               { b -= 320; in = W2; out = W2T; K = 1024; Nc = 256;  bx = b & 7;  by = b >> 3; }
    int n0 = bx * 32, k0 = by * 32;
    int tx = threadIdx.x & 31, ty = threadIdx.x >> 5;
#pragma unroll
    for (int i = 0; i < 4; ++i)
        t[ty + i * 8][tx] = in[(long)(k0 + ty + i * 8) * Nc + n0 + tx];
    __syncthreads();
#pragma unroll
    for (int i = 0; i < 4; ++i)
        out[(long)(n0 + ty + i * 8) * K + k0 + tx] = (bf16)t[tx][ty + i * 8];
}

// ---------------- bf16 MFMA GEMM: C[M][Nc] = A[M][K] * BT[Nc][K]^T ----------------
template <int EPI>
__global__ __launch_bounds__(256)
void k_gemmA(const bf16* __restrict__ A, const bf16* __restrict__ BT,
             bf16* __restrict__ C, const float* __restrict__ bias,
             const float* __restrict__ avs, const float* __restrict__ avd,
             float* __restrict__ asrcO, float* __restrict__ adstO,
             int M, int K, int Nc) {
    __shared__ __attribute__((aligned(16))) bf16 smem[17408];  // 34816 B
    bf16* As = smem;          // [128][64]
    bf16* Bs = smem + 8192;   // [128][64]
    const int tid = threadIdx.x;
    const int w = tid >> 6, lane = tid & 63;
    const int gm = blockIdx.x * 128, gn = blockIdx.y * 128;
    const int wm = (w >> 1) * 64, wn = (w & 1) * 64;
    const int lr = lane & 15, lkc = lane >> 4;

    long aoff[4], boff[4];
#pragma unroll
    for (int j = 0; j < 4; ++j) {
        int s = w * 4 + j;
        int r = s * 8 + (lane >> 3);
        int kc = ((lane & 7) ^ (r & 7)) * 8;
        aoff[j] = (long)min(gm + r, M - 1) * K + kc;
        boff[j] = (long)(gn + r) * K + kc;
    }

    floatx4 acc[4][4];
#pragma unroll
    for (int a = 0; a < 4; ++a)
#pragma unroll
        for (int b = 0; b < 4; ++b) acc[a][b] = floatx4{0.f, 0.f, 0.f, 0.f};

    for (int k0 = 0; k0 < K; k0 += 64) {
        if (k0) __syncthreads();
#pragma unroll
        for (int j = 0; j < 4; ++j) {
            int s = w * 4 + j;
            glds16(A + aoff[j] + k0, As + s * 512);
            glds16(BT + boff[j] + k0, Bs + s * 512);
        }
        __syncthreads();
#pragma unroll
        for (int kk = 0; kk < 2; ++kk) {
            bf16x8 af[4], bv[4];
#pragma unroll
            for (int mi = 0; mi < 4; ++mi) {
                int r = wm + mi * 16 + lr;
                int ch = (kk * 4 + lkc) ^ (r & 7);
                af[mi] = *(const bf16x8*)(As + r * 64 + ch * 8);
            }
#pragma unroll
            for (int ni = 0; ni < 4; ++ni) {
                int r = wn + ni * 16 + lr;
                int ch = (kk * 4 + lkc) ^ (r & 7);
                bv[ni] = *(const bf16x8*)(Bs + r * 64 + ch * 8);
            }
#pragma unroll
            for (int mi = 0; mi < 4; ++mi)
#pragma unroll
                for (int ni = 0; ni < 4; ++ni)
                    acc[mi][ni] = __builtin_amdgcn_mfma_f32_16x16x32_bf16(af[mi], bv[ni], acc[mi][ni], 0, 0, 0);
        }
    }

    __syncthreads();
    bf16* cs = smem;  // [128][136]
#pragma unroll
    for (int ni = 0; ni < 4; ++ni) {
        const int cl = wn + ni * 16 + lr;
        const float bvs = (EPI == 1) ? bias[gn + cl] : 0.f;
#pragma unroll
        for (int mi = 0; mi < 4; ++mi)
#pragma unroll
            for (int i = 0; i < 4; ++i) {
                int rl = wm + mi * 16 + lkc * 4 + i;
                float v = acc[mi][ni][i] + bvs;
                if (EPI == 1) v = gelu_f(v);
                cs[rl * 136 + cl] = (bf16)v;
            }
    }
    __syncthreads();

    const int c8 = (lane & 15) * 8;
    float as8[8], ad8[8];
    int hd = 0;
    if (EPI == 0) {
        hd = (gn >> 6) + ((lane & 15) >> 3);
        const int cb = hd * 64 + (c8 & 63);
#pragma unroll
        for (int i = 0; i < 8; ++i) { as8[i] = avs[cb + i]; ad8[i] = avd[cb + i]; }
    }

#pragma unroll
    for (int t = 0; t < 8; ++t) {
        int rl = w * 32 + t * 4 + (lane >> 4);
        int grow = gm + rl;
        uint4 val = *(const uint4*)(cs + rl * 136 + c8);
        if (grow < M) *(uint4*)(C + (long)grow * Nc + gn + c8) = val;
        if (EPI == 0) {
            float h0 = b2f_lo(val.x), h1 = b2f_hi(val.x), h2 = b2f_lo(val.y), h3 = b2f_hi(val.y);
            float h4 = b2f_lo(val.z), h5 = b2f_hi(val.z), h6 = b2f_lo(val.w), h7 = b2f_hi(val.w);
            float ds = h0 * as8[0] + h1 * as8[1] + h2 * as8[2] + h3 * as8[3]
                     + h4 * as8[4] + h5 * as8[5] + h6 * as8[6] + h7 * as8[7];
            float dd = h0 * ad8[0] + h1 * ad8[1] + h2 * ad8[2] + h3 * ad8[3]
                     + h4 * ad8[4] + h5 * ad8[5] + h6 * ad8[6] + h7 * ad8[7];
#pragma unroll
            for (int off = 1; off < 8; off <<= 1) { ds += __shfl_xor(ds, off); dd += __shfl_xor(dd, off); }
            if ((lane & 7) == 0 && grow < M) {
                asrcO[grow * 4 + hd] = ds;
                adstO[grow * 4 + hd] = dd;
            }
        }
    }
}

// ---------------- fused FFN v7b: 2-phase W double-buffer (R9-proven, 144.6us) + T5 setprio ----------------
// STAGE(c+1) issues right after the drain barrier of chunk c; loads ride across
// stageA+stageB. Mid-chunk acts barrier is raw s_barrier + lgkmcnt(0) only.
// One vmcnt(0) drain per chunk at the top __syncthreads. LDS 73728 B -> 2
// blocks/CU. setprio(1) wraps both MFMA clusters: the two independent blocks
// per CU sit at different phases, so MFMA-entering waves preempt stage waves.
#define STAGE_W(cc, pp) do {                                                    \
    bf16* w1d = smem + 4096 + (pp) * 8192;                                      \
    bf16* w2d = smem + 20480 + (pp) * 8192;                                     \
    _Pragma("unroll")                                                           \
    for (int j = 0; j < 2; ++j) {                                               \
        int sg = w * 2 + j;                                                     \
        int r = sg * 2 + (lane >> 5);                                           \
        int col = ((lane & 31) ^ (r & 7)) * 8;                                  \
        glds16(W1T + (long)((cc) * 32 + r) * DIMC + col, w1d + sg * 512);       \
    }                                                                           \
    _Pragma("unroll")                                                           \
    for (int j = 0; j < 2; ++j) {                                               \
        int sg = w * 2 + j;                                                     \
        int r = sg * 16 + (lane >> 2);                                          \
        int col = (cc) * 32 + (((lane & 3) ^ ((r >> 1) & 3)) * 8);              \
        glds16(W2T + (long)r * FFC + col, w2d + sg * 512);                      \
    }                                                                           \
} while (0)

__global__ __launch_bounds__(512)
void k_ffn(const bf16* __restrict__ x1b, const bf16* __restrict__ W1T,
           const bf16* __restrict__ W2T, const float* __restrict__ b1,
           const float* __restrict__ b2, const float* __restrict__ x,
           const float* __restrict__ lng, const float* __restrict__ lnb,
           float* __restrict__ out, int M) {
    __shared__ __attribute__((aligned(16))) bf16 smem[36864];  // 73728 B
    float* actf = (float*)smem;      // [64][32] f32, swizzled, 8 KB
    // w1 dbuf: smem+4096 + p*8192 ([32][256] each); w2 dbuf: smem+20480 + p*8192
    const int tid = threadIdx.x;
    const int w = tid >> 6, lane = tid & 63;
    const int lr = lane & 15, lkc = lane >> 4;
    const int mg = w >> 1, nh = w & 1;
    const int gm = blockIdx.x * 64;

    // persistent x1 A-fragments: rows [gm+mg*16, +16), K=256
    bf16x8 xf[8];
    {
        long rb = (long)min(gm + mg * 16 + lr, M - 1) * DIMC;
#pragma unroll
        for (int kf = 0; kf < 8; ++kf)
            xf[kf] = *(const bf16x8*)(x1b + rb + kf * 32 + lkc * 8);
    }

    floatx4 accB[8];
#pragma unroll
    for (int i = 0; i < 8; ++i) accB[i] = floatx4{0.f, 0.f, 0.f, 0.f};

    const int rbA = nh * 16 + lr;       // W1 fragment row (chunk col)
    const int rAct = mg * 16 + lr;      // acts read row
    const int kAct = nh * 16 + lr;      // acts write col

    STAGE_W(0, 0);

    for (int c = 0; c < 32; ++c) {
        const int p = c & 1;
        __syncthreads();          // drains W[c] loads (landed during prev chunk);
                                  // also: all waves done reading buf[p^1]
        if (c < 31) STAGE_W(c + 1, p ^ 1);   // in flight across stageA+stageB
        bf16* w1s = smem + 4096 + p * 8192;
        bf16* w2s = smem + 20480 + p * 8192;

        // stage A: 8 MFMA, two accumulator chains, W1 frags from LDS
        floatx4 a0 = floatx4{0.f, 0.f, 0.f, 0.f}, a1 = a0;
        __builtin_amdgcn_s_setprio(1);
#pragma unroll
        for (int kf = 0; kf < 8; kf += 2) {
            int g0 = (kf * 4 + lkc) ^ (rbA & 7);
            int g1 = ((kf + 1) * 4 + lkc) ^ (rbA & 7);
            bf16x8 bva = *(const bf16x8*)(w1s + rbA * 256 + g0 * 8);
            bf16x8 bvb = *(const bf16x8*)(w1s + rbA * 256 + g1 * 8);
            a0 = __builtin_amdgcn_mfma_f32_16x16x32_bf16(xf[kf], bva, a0, 0, 0, 0);
            a1 = __builtin_amdgcn_mfma_f32_16x16x32_bf16(xf[kf + 1], bvb, a1, 0, 0, 0);
        }
        __builtin_amdgcn_s_setprio(0);
        float b1v = b1[c * 32 + kAct];
#pragma unroll
        for (int i = 0; i < 4; ++i) {
            int r = mg * 16 + lkc * 4 + i;
            float v = gelu_f(a0[i] + a1[i] + b1v);
            actf[r * 32 + (((kAct >> 2) ^ (r & 7)) << 2) + (kAct & 3)] = v;
        }
        // acts barrier: LDS-only wait — the in-flight W[c+1] vmcnt ops stay out
        asm volatile("s_waitcnt lgkmcnt(0)" ::: "memory");
        __builtin_amdgcn_s_barrier();
        asm volatile("" ::: "memory");

        // stage B: 2 conflict-free b128 acts reads + 8 MFMA, W2 frags from LDS
        {
            int g0 = (lkc * 2) ^ (rAct & 7);
            int g1 = (lkc * 2 + 1) ^ (rAct & 7);
            float4 lo = *(const float4*)(actf + rAct * 32 + g0 * 4);
            float4 hi = *(const float4*)(actf + rAct * 32 + g1 * 4);
            bf16x8 af;
            af[0] = (bf16)lo.x; af[1] = (bf16)lo.y; af[2] = (bf16)lo.z; af[3] = (bf16)lo.w;
            af[4] = (bf16)hi.x; af[5] = (bf16)hi.y; af[6] = (bf16)hi.z; af[7] = (bf16)hi.w;
            __builtin_amdgcn_s_setprio(1);
#pragma unroll
            for (int ni = 0; ni < 8; ++ni) {
                int rb = nh * 128 + ni * 16 + lr;
                int gb = lkc ^ ((rb >> 1) & 3);
                bf16x8 bv = *(const bf16x8*)(w2s + rb * 32 + gb * 8);
                accB[ni] = __builtin_amdgcn_mfma_f32_16x16x32_bf16(af, bv, accB[ni], 0, 0, 0);
            }
            __builtin_amdgcn_s_setprio(0);
        }
    }

    // ---- epilogue: acc+b2 -> LDS bf16 [64][264] -> LN2 + residual
    __syncthreads();   // last stage-B reads done before cs overwrite
    bf16* cs = smem;   // [64][264] = 33792 B
#pragma unroll
    for (int ni = 0; ni < 8; ++ni) {
        int col = nh * 128 + ni * 16 + lr;
        float b2v = b2[col];
#pragma unroll
        for (int i = 0; i < 4; ++i) {
            int rl = mg * 16 + lkc * 4 + i;
            cs[rl * 264 + col] = (bf16)(accB[ni][i] + b2v);
        }
    }
    __syncthreads();
    float4 g4 = *(const float4*)(lng + lane * 4);
    float4 lb4 = *(const float4*)(lnb + lane * 4);
#pragma unroll 1
    for (int t = 0; t < 8; ++t) {
        int r = w * 8 + t;
        int grow = gm + r;
        long base = (long)min(grow, M - 1) * DIMC + lane * 4;
        uint2 cu = *(const uint2*)(cs + r * 264 + lane * 4);
        uint2 xu = *(const uint2*)(x1b + base);
        float v0 = b2f_lo(cu.x) + b2f_lo(xu.x);
        float v1 = b2f_hi(cu.x) + b2f_hi(xu.x);
        float v2 = b2f_lo(cu.y) + b2f_lo(xu.y);
        float v3 = b2f_hi(cu.y) + b2f_hi(xu.y);
        float s1 = v0 + v1 + v2 + v3;
        float s2 = v0 * v0 + v1 * v1 + v2 * v2 + v3 * v3;
#pragma unroll
        for (int off = 1; off < 64; off <<= 1) { s1 += __shfl_xor(s1, off); s2 += __shfl_xor(s2, off); }
        float mu = s1 * (1.f / DIMC);
        float rs = rsqrtf(s2 * (1.f / DIMC) - mu * mu + 1e-5f);
        float4 xr = *(const float4*)(x + base);
        float4 o;
        o.x = (v0 - mu) * rs * g4.x + lb4.x + xr.x;
        o.y = (v1 - mu) * rs * g4.y + lb4.y + xr.y;
        o.z = (v2 - mu) * rs * g4.z + lb4.z + xr.z;
        o.w = (v3 - mu) * rs * g4.w + lb4.w + xr.w;
        if (grow < M) *(float4*)(out + (long)grow * DIMC + lane * 4) = o;
    }
}

// ---------------- parallel 3-phase CSR scan ----------------
__global__ __launch_bounds__(1024)
void k_scan1(const unsigned* __restrict__ deg, unsigned* __restrict__ rowoff,
             unsigned* __restrict__ cursor, unsigned* __restrict__ bsum) {
    __shared__ unsigned wsum[16], wscan[16];
    int tid = threadIdx.x, lane = tid & 63, wid = tid >> 6;
    int i = blockIdx.x * 1024 + tid;
    unsigned v = (i < NN) ? deg[i] : 0u;
    unsigned s = v;
    for (int off = 1; off < 64; off <<= 1) {
        unsigned t = __shfl_up(s, off);
        if (lane >= off) s += t;
    }
    if (lane == 63) wsum[wid] = s;
    __syncthreads();
    if (wid == 0) {
        unsigned t = (lane < 16) ? wsum[lane] : 0u;
        unsigned ts = t;
        for (int off = 1; off < 16; off <<= 1) {
            unsigned u2 = __shfl_up(ts, off);
            if (lane >= off) ts += u2;
        }
        if (lane < 16) wscan[lane] = ts;
    }
    __syncthreads();
    unsigned basew = (wid > 0) ? wscan[wid - 1] : 0u;
    unsigned excl = basew + (s - v);
    if (i < NN) { rowoff[i] = excl; cursor[i] = excl; }
    if (tid == 0) bsum[blockIdx.x] = wscan[15];
}

__global__ __launch_bounds__(64)
void k_scan2(unsigned* __restrict__ bsum, unsigned* __restrict__ rowoff) {
    int lane = threadIdx.x;
    unsigned v = (lane < 49) ? bsum[lane] : 0u;
    unsigned s = v;
    for (int off = 1; off < 64; off <<= 1) {
        unsigned t = __shfl_up(s, off);
        if (lane >= off) s += t;
    }
    if (lane < 49) bsum[lane] = s - v;
    if (lane == 48) rowoff[NN] = s;
}

__global__ __launch_bounds__(256)
void k_scan3(const unsigned* __restrict__ bsum, unsigned* __restrict__ rowoff,
             unsigned* __restrict__ cursor) {
    int i = blockIdx.x * 256 + threadIdx.x;
    if (i < NN) {
        unsigned o = bsum[i >> 10];
        rowoff[i] += o;
        cursor[i] += o;
    }
}

// fill CSR + precompute per-edge src-logits in CSR order (coalesced read in agg)
__global__ __launch_bounds__(256)
void k_fill(const int* __restrict__ src, const int* __restrict__ dst,
            const float* __restrict__ asrc, unsigned* __restrict__ cursor,
            unsigned* __restrict__ elist, float4* __restrict__ evals) {
    int e = blockIdx.x * 256 + threadIdx.x;
    if (e < EE) {
        int s = src[e];
        unsigned p = atomicAdd(&cursor[dst[e]], 1u);
        elist[p] = (unsigned)s;
        evals[p] = *(const float4*)(asrc + (long)s * 4);
    }
}

// ---------------- per-node: single-pass softmax-aggregate + residual + LN1 ----------------
__global__ __launch_bounds__(256)
void k_agg_ln1(const unsigned* __restrict__ rowoff, const unsigned* __restrict__ elist,
               const float* __restrict__ evals, const float* __restrict__ adst,
               const bf16* __restrict__ hb, const float* __restrict__ x,
               const float* __restrict__ gatb, const float* __restrict__ lng,
               const float* __restrict__ lnb, bf16* __restrict__ x1b) {
    int node = (blockIdx.x * 256 + threadIdx.x) >> 6;
    int lane = threadIdx.x & 63;
    if (node >= NN) return;
    int beg = (int)rowoff[node], end = (int)rowoff[node + 1];
    int head = lane >> 4;
    float ad = adst[node * 4 + head];
    const int c = lane * 4;
    const bf16* hc = hb + c;
    const int bl = lane & 48;

    float dsum = 0.f;
    float a0 = 0.f, a1 = 0.f, a2 = 0.f, a3 = 0.f;

    for (int c0 = beg; c0 < end; c0 += 16) {
        int take = end - c0; if (take > 16) take = 16;
        int jj = c0 + (lane & 15);
        float ex = 0.f; int s = 0;
        if (jj < end) {
            s = (int)elist[jj];
            float e = evals[(long)jj * 4 + head] + ad;   // coalesced (CSR-ordered)
            e = (e > 0.f) ? e : 0.2f * e;
            ex = __expf(e);
        }
        dsum += ex;
        if (take == 16) {
#pragma unroll
            for (int j = 0; j < 16; ++j) {
                float al = __shfl(ex, bl + j);
                int sj = __shfl(s, bl + j);
                uint2 u = *(const uint2*)(hc + (long)sj * DIMC);
                a0 += al * b2f_lo(u.x);
                a1 += al * b2f_hi(u.x);
                a2 += al * b2f_lo(u.y);
                a3 += al * b2f_hi(u.y);
            }
        } else {
            for (int j = 0; j < take; ++j) {
                float al = __shfl(ex, bl + j);
                int sj = __shfl(s, bl + j);
                uint2 u = *(const uint2*)(hc + (long)sj * DIMC);
                a0 += al * b2f_lo(u.x);
                a1 += al * b2f_hi(u.x);
                a2 += al * b2f_lo(u.y);
                a3 += al * b2f_hi(u.y);
            }
        }
    }
    dsum += __shfl_xor(dsum, 1);
    dsum += __shfl_xor(dsum, 2);
    dsum += __shfl_xor(dsum, 4);
    dsum += __shfl_xor(dsum, 8);
    float invd = 1.f / (dsum + 1e-16f);
    a0 *= invd; a1 *= invd; a2 *= invd; a3 *= invd;

    long base = (long)node * DIMC + c;
    float4 xr = *(const float4*)(x + base);
    float4 gb = *(const float4*)(gatb + c);
    float v0 = xr.x + a0 + gb.x;
    float v1 = xr.y + a1 + gb.y;
    float v2 = xr.z + a2 + gb.z;
    float v3 = xr.w + a3 + gb.w;
    float s1 = v0 + v1 + v2 + v3;
    float s2 = v0 * v0 + v1 * v1 + v2 * v2 + v3 * v3;
    for (int off = 1; off < 64; off <<= 1) { s1 += __shfl_xor(s1, off); s2 += __shfl_xor(s2, off); }
    float mu = s1 * (1.f / DIMC);
    float rs = rsqrtf(s2 * (1.f / DIMC) - mu * mu + 1e-5f);
    float4 g4 = *(const float4*)(lng + c);
    float4 b4 = *(const float4*)(lnb + c);
    float y0 = (v0 - mu) * rs * g4.x + b4.x;
    float y1 = (v1 - mu) * rs * g4.y + b4.y;
    float y2 = (v2 - mu) * rs * g4.z + b4.z;
    float y3 = (v3 - mu) * rs * g4.w + b4.w;
    uint2 p;
    p.x = (unsigned)f2b(y0) | ((unsigned)f2b(y1) << 16);
    p.y = (unsigned)f2b(y2) | ((unsigned)f2b(y3) << 16);
    *(uint2*)(x1b + base) = p;
}

extern "C" void kernel_launch(void* const* d_in, const int* in_sizes, int n_in,
                              void* d_out, int out_size, void* d_ws, size_t ws_size,
                              hipStream_t stream) {
    const float* x    = (const float*)d_in[0];
    const int*   ei   = (const int*)d_in[1];
    const float* W    = (const float*)d_in[2];
    const float* a_s  = (const float*)d_in[3];
    const float* a_d  = (const float*)d_in[4];
    const float* gatb = (const float*)d_in[5];
    const float* lng  = (const float*)d_in[6];
    const float* lnb  = (const float*)d_in[7];
    const float* W1   = (const float*)d_in[8];
    const float* b1   = (const float*)d_in[9];
    const float* W2   = (const float*)d_in[10];
    const float* b2   = (const float*)d_in[11];
    float* out = (float*)d_out;
    char* ws = (char*)d_ws;

    bf16*     xb     = (bf16*)(ws + 0L);
    bf16*     hb     = (bf16*)(ws + 25600000L);
    bf16*     x1b    = (bf16*)(ws + 51200000L);
    unsigned* bsum   = (unsigned*)(ws + 76800000L);   // 49 entries
    float4*   evals  = (float4*)(ws + 77000032L);     // [E] float4 = 12.8 MB (dead region)
    float*    asrc   = (float*)(ws + 179200000L);
    float*    adst   = (float*)(ws + 180000000L);
    unsigned* deg    = (unsigned*)(ws + 180800000L);
    unsigned* cursor = (unsigned*)(ws + 181000192L);
    unsigned* rowoff = (unsigned*)(ws + 181200384L);
    unsigned* elist  = (unsigned*)(ws + 181400832L);
    bf16*     WT     = (bf16*)(ws + 184600832L);
    bf16*     W1T    = (bf16*)(ws + 184731904L);
    bf16*     W2T    = (bf16*)(ws + 185256192L);

    const int* esrc = ei;
    const int* edst = ei + EE;

    hipMemsetAsync(deg, 0, NN * sizeof(unsigned), stream);
    k_cast_count<<<12500, 256, 0, stream>>>(x, xb, (long)NN * DIMC / 4, edst, deg);
    k_tcast_all<<<576, 256, 0, stream>>>(W, WT, W1, W1T, W2, W2T);

    dim3 g1(391, 2);
    k_gemmA<0><<<g1, 256, 0, stream>>>(xb, WT, hb, nullptr, a_s, a_d, asrc, adst, NN, DIMC, DIMC);

    k_scan1<<<49, 1024, 0, stream>>>(deg, rowoff, cursor, bsum);
    k_scan2<<<1, 64, 0, stream>>>(bsum, rowoff);
    k_scan3<<<196, 256, 0, stream>>>(bsum, rowoff, cursor);
    k_fill<<<3125, 256, 0, stream>>>(esrc, edst, asrc, cursor, elist, evals);

    k_agg_ln1<<<12500, 256, 0, stream>>>(rowoff, elist, (const float*)evals, adst, hb, x, gatb, lng, lnb, x1b);

    k_ffn<<<782, 512, 0, stream>>>(x1b, W1T, W2T, b1, b2, x, lng, lnb, out, NN);
}